// Round 1
// baseline (665.404 us; speedup 1.0000x reference)
//
#include <hip/hip_runtime.h>
#include <stdint.h>

typedef short bf16x8 __attribute__((ext_vector_type(8)));
typedef float f32x4 __attribute__((ext_vector_type(4)));

#define SEQ     2048
#define DM      4096
#define NQH     32
#define NKVH    8
#define DK      128
#define NQKV    6144   // 4096 q + 1024 k + 1024 v

// ---------- helpers ----------
__device__ __forceinline__ unsigned short f2bfb(float f) {
    union { float f; unsigned u; } x; x.f = f;
    unsigned r = x.u + 0x7FFFu + ((x.u >> 16) & 1u);   // RNE
    return (unsigned short)(r >> 16);
}

__device__ __forceinline__ void stage16(const void* g, void* l) {
    __builtin_amdgcn_global_load_lds(
        (const __attribute__((address_space(1))) void*)g,
        (__attribute__((address_space(3))) void*)l,
        16, 0, 0);
}

// ---------- fp32 -> bf16 conversion (vectorized, grid-stride) ----------
__global__ __launch_bounds__(256)
void cvt_bf16(const float4* __restrict__ src, ushort4* __restrict__ dst, int n4) {
    int i = blockIdx.x * 256 + threadIdx.x;
    const int stride = gridDim.x * 256;
    for (; i < n4; i += stride) {
        float4 f = src[i];
        ushort4 u;
        u.x = f2bfb(f.x); u.y = f2bfb(f.y); u.z = f2bfb(f.z); u.w = f2bfb(f.w);
        dst[i] = u;
    }
}

// ---------- GEMM: C[M][N] = A[M][K](bf16) * B[N][K](bf16)^T, fp32 out ----------
// 128x128 tile, BK=32, 4 waves in 2x2 of 64x64, global_load_lds staging.
__global__ __launch_bounds__(256, 2)
void gemm_bt(const unsigned short* __restrict__ A, const unsigned short* __restrict__ B,
             float* __restrict__ C, int M, int N, int K)
{
    __shared__ __align__(16) unsigned short As[128 * 32];
    __shared__ __align__(16) unsigned short Bs[128 * 32];

    const int tid = threadIdx.x;
    const int w  = tid >> 6;
    const int l  = tid & 63;
    const int lr = l & 15;
    const int lg = l >> 4;
    const int m0 = blockIdx.y << 7;
    const int n0 = blockIdx.x << 7;
    const int wm = (w >> 1) << 6;
    const int wn = (w & 1) << 6;

    f32x4 acc[4][4];
#pragma unroll
    for (int i = 0; i < 4; ++i)
#pragma unroll
        for (int j = 0; j < 4; ++j) acc[i][j] = f32x4{0.f, 0.f, 0.f, 0.f};

    // staging geometry: chunk c in [0,512), 16B each; row = c>>2, kchunk = (c&3)*8 elems
    const int c0   = tid;
    const int row0 = c0 >> 2, kc0 = (c0 & 3) << 3;
    const int c1   = tid + 256;
    const int row1 = c1 >> 2, kc1 = (c1 & 3) << 3;
    const unsigned short* Ag = A + (size_t)m0 * K;
    const unsigned short* Bg = B + (size_t)n0 * K;
    char* AsB = (char*)As;
    char* BsB = (char*)Bs;
    const int wb = w << 10;   // wave's 1KB LDS slice per round

    const int nk = K >> 5;
    for (int kt = 0; kt < nk; ++kt) {
        const int ko = kt << 5;
        stage16(Ag + (size_t)row0 * K + ko + kc0, AsB + wb);
        stage16(Ag + (size_t)row1 * K + ko + kc1, AsB + 4096 + wb);
        stage16(Bg + (size_t)row0 * K + ko + kc0, BsB + wb);
        stage16(Bg + (size_t)row1 * K + ko + kc1, BsB + 4096 + wb);
        __syncthreads();   // drains vmcnt -> tiles visible

        bf16x8 af[4], bfr[4];
#pragma unroll
        for (int mi = 0; mi < 4; ++mi)
            af[mi] = *(const bf16x8*)(As + ((wm + (mi << 4) + lr) << 5) + (lg << 3));
#pragma unroll
        for (int ni = 0; ni < 4; ++ni)
            bfr[ni] = *(const bf16x8*)(Bs + ((wn + (ni << 4) + lr) << 5) + (lg << 3));
#pragma unroll
        for (int mi = 0; mi < 4; ++mi)
#pragma unroll
            for (int ni = 0; ni < 4; ++ni)
                acc[mi][ni] = __builtin_amdgcn_mfma_f32_16x16x32_bf16(af[mi], bfr[ni], acc[mi][ni], 0, 0, 0);
        __syncthreads();   // protect LDS before next stage
    }

#pragma unroll
    for (int mi = 0; mi < 4; ++mi)
#pragma unroll
        for (int ni = 0; ni < 4; ++ni) {
            const int row = m0 + wm + (mi << 4) + (lg << 2);
            const int col = n0 + wn + (ni << 4) + lr;
            float* cp = C + (size_t)row * N + col;
#pragma unroll
            for (int r = 0; r < 4; ++r) cp[(size_t)r * N] = acc[mi][ni][r];
        }
}

// ---------- per-head LayerNorm on q/k segments of Y, writes bf16 ----------
// Y: [SEQ][6144] fp32. Segment g = s*40 + hh, hh in [0,40): 32 q heads then 8 k heads.
// Q out: [32][SEQ][128] bf16 ; K out: [8][SEQ][128] bf16.
__global__ __launch_bounds__(256)
void ln_qk(const float* __restrict__ Y,
           const float* __restrict__ qg, const float* __restrict__ qb,
           const float* __restrict__ kg, const float* __restrict__ kb,
           unsigned short* __restrict__ Q, unsigned short* __restrict__ Kc)
{
    const int seg = blockIdx.x * 4 + (threadIdx.x >> 6);
    const int l = threadIdx.x & 63;
    const int s = seg / 40;
    const int hh = seg - s * 40;

    const float* y = Y + (size_t)s * NQKV + hh * 128;
    float2 v = *(const float2*)(y + l * 2);
    float sum = v.x + v.y;
    float sq  = v.x * v.x + v.y * v.y;
#pragma unroll
    for (int d = 1; d < 64; d <<= 1) {
        sum += __shfl_xor(sum, d);
        sq  += __shfl_xor(sq, d);
    }
    const float mu  = sum * (1.f / 128.f);
    const float var = sq * (1.f / 128.f) - mu * mu;
    const float rs  = rsqrtf(var + 1e-6f);

    const float* g = (hh < 32) ? qg : kg;
    const float* b = (hh < 32) ? qb : kb;
    const float g0 = g[l * 2], g1 = g[l * 2 + 1];
    const float b0 = b[l * 2], b1 = b[l * 2 + 1];
    const unsigned short o0 = f2bfb((v.x - mu) * rs * g0 + b0);
    const unsigned short o1 = f2bfb((v.y - mu) * rs * g1 + b1);
    const unsigned pack = (unsigned)o0 | ((unsigned)o1 << 16);

    if (hh < 32) {
        unsigned* dst = (unsigned*)(Q + ((size_t)hh * SEQ + s) * 128 + l * 2);
        *dst = pack;
    } else {
        unsigned* dst = (unsigned*)(Kc + ((size_t)(hh - 32) * SEQ + s) * 128 + l * 2);
        *dst = pack;
    }
}

// ---------- V transpose: Y v-columns -> Vt[8][128][SEQ] bf16 ----------
__global__ __launch_bounds__(256)
void v_transpose(const float* __restrict__ Y, unsigned short* __restrict__ Vt)
{
    __shared__ unsigned short t[64][132];
    const int h  = blockIdx.x;       // kv head
    const int s0 = blockIdx.y << 6;  // 64-row block of tokens
    const int tid = threadIdx.x;
    const float* y = Y + (size_t)s0 * NQKV + 5120 + h * 128;

#pragma unroll
    for (int p = 0; p < 16; ++p) {
        const int idx = p * 512 + tid * 2;
        const int s = idx >> 7, d = idx & 127;
        float2 v = *(const float2*)(y + (size_t)s * NQKV + d);
        t[s][d]     = f2bfb(v.x);
        t[s][d + 1] = f2bfb(v.y);
    }
    __syncthreads();
    unsigned short* out = Vt + (size_t)h * 128 * SEQ + s0;
#pragma unroll
    for (int p = 0; p < 16; ++p) {
        const int idx = p * 512 + tid * 2;
        const int d = idx >> 6, sp = idx & 63;
        unsigned pack = (unsigned)t[sp][d] | ((unsigned)t[sp + 1][d] << 16);
        *(unsigned*)(out + (size_t)d * SEQ + sp) = pack;
    }
}

// ---------- causal GQA flash attention ----------
// Q: [32][SEQ][128], K: [8][SEQ][128], Vt: [8][128][SEQ] (all bf16)
// Ob: [SEQ][4096] bf16 (token-major, ready as GEMM2's A)
__global__ __launch_bounds__(256, 2)
void attn(const unsigned short* __restrict__ Qb, const unsigned short* __restrict__ Kb,
          const unsigned short* __restrict__ Vt, unsigned short* __restrict__ Ob)
{
    __shared__ __align__(16) unsigned short pl[4][32][72];   // per-wave P buffer, padded
    const int h   = blockIdx.x;
    const int qt  = 15 - blockIdx.y;        // heavy (long) q-tiles first
    const int kvh = h >> 2;
    const int tid = threadIdx.x;
    const int w  = tid >> 6;
    const int l  = tid & 63;
    const int lr = l & 15;
    const int lg = l >> 4;
    const int q0   = qt << 7;
    const int wrow = w << 5;

    const unsigned short* Qh  = Qb + ((size_t)h * SEQ + q0 + wrow) * 128;
    const unsigned short* Kh0 = Kb + (size_t)kvh * SEQ * 128;
    const unsigned short* Vh  = Vt + (size_t)kvh * 128 * SEQ;

    // Q fragments live in registers for the whole block
    bf16x8 qf[2][4];
#pragma unroll
    for (int mi = 0; mi < 2; ++mi)
#pragma unroll
        for (int ks = 0; ks < 4; ++ks)
            qf[mi][ks] = *(const bf16x8*)(Qh + ((mi << 4) + lr) * 128 + (ks << 5) + (lg << 3));

    f32x4 o[2][8];
    float m_run[2][4], l_run[2][4];
#pragma unroll
    for (int mi = 0; mi < 2; ++mi) {
#pragma unroll
        for (int nf = 0; nf < 8; ++nf) o[mi][nf] = f32x4{0.f, 0.f, 0.f, 0.f};
#pragma unroll
        for (int r = 0; r < 4; ++r) { m_run[mi][r] = -3.0e38f; l_run[mi][r] = 0.f; }
    }

    const float scale = 0.08838834764831845f;   // 1/sqrt(128)
    const int nkv = q0 + 128;

    for (int kv0 = 0; kv0 < nkv; kv0 += 64) {
        // ---- S = Q K^T over this 128x64 tile ----
        f32x4 sc[2][4];
#pragma unroll
        for (int mi = 0; mi < 2; ++mi)
#pragma unroll
            for (int ni = 0; ni < 4; ++ni) sc[mi][ni] = f32x4{0.f, 0.f, 0.f, 0.f};

        const unsigned short* Kh = Kh0 + (size_t)kv0 * 128;
#pragma unroll
        for (int ks = 0; ks < 4; ++ks) {
            bf16x8 kf[4];
#pragma unroll
            for (int ni = 0; ni < 4; ++ni)
                kf[ni] = *(const bf16x8*)(Kh + ((ni << 4) + lr) * 128 + (ks << 5) + (lg << 3));
#pragma unroll
            for (int mi = 0; mi < 2; ++mi)
#pragma unroll
                for (int ni = 0; ni < 4; ++ni)
                    sc[mi][ni] = __builtin_amdgcn_mfma_f32_16x16x32_bf16(qf[mi][ks], kf[ni], sc[mi][ni], 0, 0, 0);
        }

        // ---- scale (+ causal mask on diagonal tiles) ----
        if (kv0 >= q0) {
#pragma unroll
            for (int mi = 0; mi < 2; ++mi)
#pragma unroll
                for (int ni = 0; ni < 4; ++ni)
#pragma unroll
                    for (int r = 0; r < 4; ++r) {
                        const int qr = q0 + wrow + (mi << 4) + (lg << 2) + r;
                        const int kc = kv0 + (ni << 4) + lr;
                        sc[mi][ni][r] = (kc <= qr) ? sc[mi][ni][r] * scale : -1.0e30f;
                    }
        } else {
#pragma unroll
            for (int mi = 0; mi < 2; ++mi)
#pragma unroll
                for (int ni = 0; ni < 4; ++ni)
#pragma unroll
                    for (int r = 0; r < 4; ++r) sc[mi][ni][r] *= scale;
        }

        // ---- online softmax (rows live across the 16-lane groups) ----
#pragma unroll
        for (int mi = 0; mi < 2; ++mi)
#pragma unroll
            for (int r = 0; r < 4; ++r) {
                float mx = fmaxf(fmaxf(sc[mi][0][r], sc[mi][1][r]),
                                 fmaxf(sc[mi][2][r], sc[mi][3][r]));
#pragma unroll
                for (int dd = 1; dd < 16; dd <<= 1) mx = fmaxf(mx, __shfl_xor(mx, dd));
                const float mold = m_run[mi][r];
                const float mnew = fmaxf(mold, mx);
                const float alpha = __expf(mold - mnew);
                m_run[mi][r] = mnew;
                float rs = 0.f;
#pragma unroll
                for (int ni = 0; ni < 4; ++ni) {
                    const float p = __expf(sc[mi][ni][r] - mnew);
                    sc[mi][ni][r] = p;
                    rs += p;
                }
#pragma unroll
                for (int dd = 1; dd < 16; dd <<= 1) rs += __shfl_xor(rs, dd);
                l_run[mi][r] = l_run[mi][r] * alpha + rs;
#pragma unroll
                for (int nf = 0; nf < 8; ++nf) o[mi][nf][r] *= alpha;
            }

        // ---- P (C-layout) -> LDS -> A-layout fragments ----
#pragma unroll
        for (int mi = 0; mi < 2; ++mi)
#pragma unroll
            for (int ni = 0; ni < 4; ++ni)
#pragma unroll
                for (int r = 0; r < 4; ++r)
                    pl[w][(mi << 4) + (lg << 2) + r][(ni << 4) + lr] = f2bfb(sc[mi][ni][r]);

        // ---- O += P V ----
#pragma unroll
        for (int ks = 0; ks < 2; ++ks) {
            bf16x8 pa[2];
#pragma unroll
            for (int mi = 0; mi < 2; ++mi)
                pa[mi] = *(const bf16x8*)(&pl[w][(mi << 4) + lr][(ks << 5) + (lg << 3)]);
#pragma unroll
            for (int nf = 0; nf < 8; ++nf) {
                const bf16x8 vf = *(const bf16x8*)(Vh + (size_t)((nf << 4) + lr) * SEQ
                                                   + kv0 + (ks << 5) + (lg << 3));
#pragma unroll
                for (int mi = 0; mi < 2; ++mi)
                    o[mi][nf] = __builtin_amdgcn_mfma_f32_16x16x32_bf16(pa[mi], vf, o[mi][nf], 0, 0, 0);
            }
        }
    }

    // ---- epilogue: normalize, write token-major bf16 ----
#pragma unroll
    for (int mi = 0; mi < 2; ++mi)
#pragma unroll
        for (int r = 0; r < 4; ++r) {
            const float inv = 1.f / l_run[mi][r];
            const int qr = q0 + wrow + (mi << 4) + (lg << 2) + r;
            unsigned short* op = Ob + (size_t)qr * DM + h * 128;
#pragma unroll
            for (int nf = 0; nf < 8; ++nf)
                op[(nf << 4) + lr] = f2bfb(o[mi][nf][r] * inv);
        }
}

// ---------- launch ----------
extern "C" void kernel_launch(void* const* d_in, const int* in_sizes, int n_in,
                              void* d_out, int out_size, void* d_ws, size_t ws_size,
                              hipStream_t stream)
{
    const float* x  = (const float*)d_in[0];
    const float* Wq = (const float*)d_in[3];
    const float* Wk = (const float*)d_in[4];
    const float* Wv = (const float*)d_in[5];
    const float* Wo = (const float*)d_in[6];
    const float* qg = (const float*)d_in[7];
    const float* qb = (const float*)d_in[8];
    const float* kg = (const float*)d_in[9];
    const float* kb = (const float*)d_in[10];
    float* out = (float*)d_out;

    char* ws = (char*)d_ws;
    unsigned short* xb   = (unsigned short*)(ws);                       // 16.8 MB
    unsigned short* wqkv = (unsigned short*)(ws + 16777216);            // 50.3 MB
    unsigned short* wo   = (unsigned short*)(ws + 67108864);            // 33.6 MB
    float*          y    = (float*)        (ws + 100663296);            // 50.3 MB
    unsigned short* qbuf = (unsigned short*)(ws + 150994944);           // 16.8 MB
    unsigned short* kbuf = (unsigned short*)(ws + 167772160);           //  4.2 MB
    unsigned short* vtb  = (unsigned short*)(ws + 171966464);           //  4.2 MB
    unsigned short* ob   = (unsigned short*)(ws + 176160768);           // 16.8 MB

    // 1) fp32 -> bf16 conversions
    {
        int n4 = (SEQ * DM) / 4;
        cvt_bf16<<<2048, 256, 0, stream>>>((const float4*)x, (ushort4*)xb, n4);
        n4 = (NQH * DK * DM) / 4;
        cvt_bf16<<<2048, 256, 0, stream>>>((const float4*)Wq, (ushort4*)wqkv, n4);
        n4 = (NKVH * DK * DM) / 4;
        cvt_bf16<<<2048, 256, 0, stream>>>((const float4*)Wk, (ushort4*)(wqkv + 16777216), n4);
        cvt_bf16<<<2048, 256, 0, stream>>>((const float4*)Wv, (ushort4*)(wqkv + 20971520), n4);
        n4 = (DM * DM) / 4;
        cvt_bf16<<<2048, 256, 0, stream>>>((const float4*)Wo, (ushort4*)wo, n4);
    }

    // 2) fused QKV projection: Y[2048][6144] = xb @ wqkv^T
    gemm_bt<<<dim3(NQKV / 128, SEQ / 128), 256, 0, stream>>>(xb, wqkv, y, SEQ, NQKV, DM);

    // 3) per-head LN on q,k -> bf16 head-major buffers
    ln_qk<<<(SEQ * 40) / 4, 256, 0, stream>>>(y, qg, qb, kg, kb, qbuf, kbuf);

    // 4) V transpose -> Vt[8][128][2048]
    v_transpose<<<dim3(NKVH, SEQ / 64), 256, 0, stream>>>(y, vtb);

    // 5) causal GQA flash attention -> ob[2048][4096]
    attn<<<dim3(NQH, SEQ / 128), 256, 0, stream>>>(qbuf, kbuf, vtb, ob);

    // 6) output projection: out = ob @ wo^T (fp32 out)
    gemm_bt<<<dim3(DM / 128, SEQ / 128), 256, 0, stream>>>(ob, wo, out, SEQ, DM, DM);
}

// Round 3
// 641.555 us; speedup vs baseline: 1.0372x; 1.0372x over previous
//
#include <hip/hip_runtime.h>
#include <stdint.h>

typedef short bf16x8 __attribute__((ext_vector_type(8)));
typedef float f32x4 __attribute__((ext_vector_type(4)));
typedef float f32x16 __attribute__((ext_vector_type(16)));

#define SEQ     2048
#define DM      4096
#define NQH     32
#define NKVH    8
#define DK      128
#define NQKV    6144   // 4096 q + 1024 k + 1024 v

// ---------- helpers ----------
__device__ __forceinline__ unsigned short f2bfb(float f) {
    union { float f; unsigned u; } x; x.f = f;
    unsigned r = x.u + 0x7FFFu + ((x.u >> 16) & 1u);   // RNE
    return (unsigned short)(r >> 16);
}

__device__ __forceinline__ unsigned cvt_pk_bf16(float a, float b) {
    unsigned r;
    asm("v_cvt_pk_bf16_f32 %0, %1, %2" : "=v"(r) : "v"(a), "v"(b));
    return r;
}

#if __has_builtin(__builtin_amdgcn_exp2f)
__device__ __forceinline__ float exp2_fast(float x) { return __builtin_amdgcn_exp2f(x); }
#else
__device__ __forceinline__ float exp2_fast(float x) { return exp2f(x); }
#endif

__device__ __forceinline__ void stage16(const void* g, void* l) {
    __builtin_amdgcn_global_load_lds(
        (const __attribute__((address_space(1))) void*)g,
        (__attribute__((address_space(3))) void*)l,
        16, 0, 0);
}

// ---------- fp32 -> bf16 conversion (vectorized, grid-stride) ----------
__global__ __launch_bounds__(256)
void cvt_bf16(const float4* __restrict__ src, ushort4* __restrict__ dst, int n4) {
    int i = blockIdx.x * 256 + threadIdx.x;
    const int stride = gridDim.x * 256;
    for (; i < n4; i += stride) {
        float4 f = src[i];
        ushort4 u;
        u.x = f2bfb(f.x); u.y = f2bfb(f.y); u.z = f2bfb(f.z); u.w = f2bfb(f.w);
        dst[i] = u;
    }
}

// ---------- GEMM: C[M][N] = A[M][K](bf16) * B[N][K](bf16)^T, fp32 out ----------
__global__ __launch_bounds__(256, 2)
void gemm_bt(const unsigned short* __restrict__ A, const unsigned short* __restrict__ B,
             float* __restrict__ C, int M, int N, int K)
{
    __shared__ __align__(16) unsigned short As[128 * 32];
    __shared__ __align__(16) unsigned short Bs[128 * 32];

    const int tid = threadIdx.x;
    const int w  = tid >> 6;
    const int l  = tid & 63;
    const int lr = l & 15;
    const int lg = l >> 4;
    const int m0 = blockIdx.y << 7;
    const int n0 = blockIdx.x << 7;
    const int wm = (w >> 1) << 6;
    const int wn = (w & 1) << 6;

    f32x4 acc[4][4];
#pragma unroll
    for (int i = 0; i < 4; ++i)
#pragma unroll
        for (int j = 0; j < 4; ++j) acc[i][j] = f32x4{0.f, 0.f, 0.f, 0.f};

    const int c0   = tid;
    const int row0 = c0 >> 2, kc0 = (c0 & 3) << 3;
    const int c1   = tid + 256;
    const int row1 = c1 >> 2, kc1 = (c1 & 3) << 3;
    const unsigned short* Ag = A + (size_t)m0 * K;
    const unsigned short* Bg = B + (size_t)n0 * K;
    char* AsB = (char*)As;
    char* BsB = (char*)Bs;
    const int wb = w << 10;

    const int nk = K >> 5;
    for (int kt = 0; kt < nk; ++kt) {
        const int ko = kt << 5;
        stage16(Ag + (size_t)row0 * K + ko + kc0, AsB + wb);
        stage16(Ag + (size_t)row1 * K + ko + kc1, AsB + 4096 + wb);
        stage16(Bg + (size_t)row0 * K + ko + kc0, BsB + wb);
        stage16(Bg + (size_t)row1 * K + ko + kc1, BsB + 4096 + wb);
        __syncthreads();

        bf16x8 af[4], bfr[4];
#pragma unroll
        for (int mi = 0; mi < 4; ++mi)
            af[mi] = *(const bf16x8*)(As + ((wm + (mi << 4) + lr) << 5) + (lg << 3));
#pragma unroll
        for (int ni = 0; ni < 4; ++ni)
            bfr[ni] = *(const bf16x8*)(Bs + ((wn + (ni << 4) + lr) << 5) + (lg << 3));
#pragma unroll
        for (int mi = 0; mi < 4; ++mi)
#pragma unroll
            for (int ni = 0; ni < 4; ++ni)
                acc[mi][ni] = __builtin_amdgcn_mfma_f32_16x16x32_bf16(af[mi], bfr[ni], acc[mi][ni], 0, 0, 0);
        __syncthreads();
    }

#pragma unroll
    for (int mi = 0; mi < 4; ++mi)
#pragma unroll
        for (int ni = 0; ni < 4; ++ni) {
            const int row = m0 + wm + (mi << 4) + (lg << 2);
            const int col = n0 + wn + (ni << 4) + lr;
            float* cp = C + (size_t)row * N + col;
#pragma unroll
            for (int r = 0; r < 4; ++r) cp[(size_t)r * N] = acc[mi][ni][r];
        }
}

// ---------- per-head LayerNorm on q/k segments of Y, writes bf16 ----------
// Folds softmax scale*log2(e) into q-head outputs.
__global__ __launch_bounds__(256)
void ln_qk(const float* __restrict__ Y,
           const float* __restrict__ qg, const float* __restrict__ qb,
           const float* __restrict__ kg, const float* __restrict__ kb,
           unsigned short* __restrict__ Q, unsigned short* __restrict__ Kc)
{
    const int seg = blockIdx.x * 4 + (threadIdx.x >> 6);
    const int l = threadIdx.x & 63;
    const int s = seg / 40;
    const int hh = seg - s * 40;

    const float* y = Y + (size_t)s * NQKV + hh * 128;
    float2 v = *(const float2*)(y + l * 2);
    float sum = v.x + v.y;
    float sq  = v.x * v.x + v.y * v.y;
#pragma unroll
    for (int d = 1; d < 64; d <<= 1) {
        sum += __shfl_xor(sum, d);
        sq  += __shfl_xor(sq, d);
    }
    const float mu  = sum * (1.f / 128.f);
    const float var = sq * (1.f / 128.f) - mu * mu;
    const float rs  = rsqrtf(var + 1e-6f);

    const float* g = (hh < 32) ? qg : kg;
    const float* b = (hh < 32) ? qb : kb;
    // fold 1/sqrt(128)*log2(e) into the q-head LN output
    const float c = (hh < 32) ? (0.08838834764831845f * 1.4426950408889634f) : 1.0f;
    const float g0 = g[l * 2], g1 = g[l * 2 + 1];
    const float b0 = b[l * 2], b1 = b[l * 2 + 1];
    const unsigned short o0 = f2bfb(((v.x - mu) * rs * g0 + b0) * c);
    const unsigned short o1 = f2bfb(((v.y - mu) * rs * g1 + b1) * c);
    const unsigned pack = (unsigned)o0 | ((unsigned)o1 << 16);

    if (hh < 32) {
        unsigned* dst = (unsigned*)(Q + ((size_t)hh * SEQ + s) * 128 + l * 2);
        *dst = pack;
    } else {
        unsigned* dst = (unsigned*)(Kc + ((size_t)(hh - 32) * SEQ + s) * 128 + l * 2);
        *dst = pack;
    }
}

// ---------- V transpose: Y v-columns -> Vt[8][128][SEQ] bf16 ----------
__global__ __launch_bounds__(256)
void v_transpose(const float* __restrict__ Y, unsigned short* __restrict__ Vt)
{
    __shared__ unsigned short t[64][132];
    const int h  = blockIdx.x;
    const int s0 = blockIdx.y << 6;
    const int tid = threadIdx.x;
    const float* y = Y + (size_t)s0 * NQKV + 5120 + h * 128;

#pragma unroll
    for (int p = 0; p < 16; ++p) {
        const int idx = p * 512 + tid * 2;
        const int s = idx >> 7, d = idx & 127;
        float2 v = *(const float2*)(y + (size_t)s * NQKV + d);
        t[s][d]     = f2bfb(v.x);
        t[s][d + 1] = f2bfb(v.y);
    }
    __syncthreads();
    unsigned short* out = Vt + (size_t)h * 128 * SEQ + s0;
#pragma unroll
    for (int p = 0; p < 16; ++p) {
        const int idx = p * 512 + tid * 2;
        const int d = idx >> 6, sp = idx & 63;
        unsigned pack = (unsigned)t[sp][d] | ((unsigned)t[sp + 1][d] << 16);
        *(unsigned*)(out + (size_t)d * SEQ + sp) = pack;
    }
}

// ---------- causal GQA flash attention, swapped-operand 32x32 structure ----------
// Q: [32][SEQ][128] (pre-scaled by 1/sqrt(d)*log2e), K: [8][SEQ][128],
// Vt: [8][128][SEQ], Ob: [SEQ][4096] bf16.
// Per wave: 32 q rows (q = lane&31). QK^T swapped: S^T = mfma(K,Q) -> lane
// holds P[q][kv] for its own q row. PV swapped: O^T = mfma(V^T, P^T) -> lane
// holds O[q][d-subset]. Softmax entirely in-lane; lane+-32 exchange via shfl.
__global__ __launch_bounds__(256, 2)
void attn(const unsigned short* __restrict__ Qb, const unsigned short* __restrict__ Kb,
          const unsigned short* __restrict__ Vt, unsigned short* __restrict__ Ob)
{
    const int h   = blockIdx.x;
    const int qt  = 15 - blockIdx.y;        // heavy q-tiles first
    const int kvh = h >> 2;
    const int tid = threadIdx.x;
    const int w   = tid >> 6;
    const int l   = tid & 63;
    const int lq  = l & 31;                 // this lane's q (within wave)
    const int hi  = l >> 5;
    const int q0  = qt << 7;
    const int wq  = q0 + (w << 5);          // wave's q base
    const int qrow = wq + lq;

    const unsigned short* Qh = Qb + ((size_t)h * SEQ + wq) * 128;
    const unsigned short* Kh = Kb + (size_t)kvh * SEQ * 128;
    const unsigned short* Vh = Vt + (size_t)kvh * 128 * SEQ;

    // Q fragments (B-operand layout: col=lane&31=q, k-chunk = hi*8), all 8 d-steps
    bf16x8 qf[8];
#pragma unroll
    for (int ks = 0; ks < 8; ++ks)
        qf[ks] = *(const bf16x8*)(Qh + lq * 128 + ks * 16 + hi * 8);

    f32x16 o0_ = {0}, o1_ = {0}, o2_ = {0}, o3_ = {0};
    float m = -1.0e30f, lsum = 0.f;

    const int kv_end = wq + 32;             // exclusive causal bound for this wave

    for (int kv0 = 0; kv0 < kv_end; kv0 += 64) {
        // ---- S^T = K Q^T : two 32-kv blocks ----
        f32x16 s0 = {0}, s1 = {0};
        const unsigned short* K0 = Kh + (size_t)kv0 * 128;
#pragma unroll
        for (int ks = 0; ks < 8; ++ks) {
            bf16x8 ka = *(const bf16x8*)(K0 + (size_t)lq * 128 + ks * 16 + hi * 8);
            bf16x8 kb2 = *(const bf16x8*)(K0 + (size_t)(32 + lq) * 128 + ks * 16 + hi * 8);
            s0 = __builtin_amdgcn_mfma_f32_32x32x16_bf16(ka, qf[ks], s0, 0, 0, 0);
            s1 = __builtin_amdgcn_mfma_f32_32x32x16_bf16(kb2, qf[ks], s1, 0, 0, 0);
        }

        // ---- causal mask (diagonal-crossing tiles only) ----
        if (kv0 + 63 > wq) {
#pragma unroll
            for (int r = 0; r < 16; ++r) {
                const int kvl = (r & 3) + 8 * (r >> 2) + 4 * hi;
                if (kv0 + kvl > qrow)      s0[r] = -1.0e30f;
                if (kv0 + 32 + kvl > qrow) s1[r] = -1.0e30f;
            }
        }

        // ---- in-lane row max over 32 values + cross-half combine ----
        float pm = s0[0];
#pragma unroll
        for (int r = 1; r < 16; ++r) pm = fmaxf(pm, s0[r]);
#pragma unroll
        for (int r = 0; r < 16; ++r) pm = fmaxf(pm, s1[r]);
        pm = fmaxf(pm, __shfl_xor(pm, 32));

        // ---- defer-max (T13): rescale only when max grew past threshold ----
        if (!__all(pm - m <= 8.0f)) {
            const float mn = fmaxf(m, pm);
            const float al = exp2_fast(m - mn);
            lsum *= al;
#pragma unroll
            for (int r = 0; r < 16; ++r) { o0_[r] *= al; o1_[r] *= al; o2_[r] *= al; o3_[r] *= al; }
            m = mn;
        }

        // ---- p = exp2(s - m), row sum ----
        float rs = 0.f;
#pragma unroll
        for (int r = 0; r < 16; ++r) { s0[r] = exp2_fast(s0[r] - m); rs += s0[r]; }
#pragma unroll
        for (int r = 0; r < 16; ++r) { s1[r] = exp2_fast(s1[r] - m); rs += s1[r]; }
        rs += __shfl_xor(rs, 32);
        lsum += rs;

        // ---- pack P to bf16 pair-words: w0/w1[b][u], kv = 32b + 8u + 4hi + {0,1}/{2,3} ----
        unsigned pw0[2][4], pw1[2][4];
#pragma unroll
        for (int u = 0; u < 4; ++u) {
            pw0[0][u] = cvt_pk_bf16(s0[u * 4 + 0], s0[u * 4 + 1]);
            pw1[0][u] = cvt_pk_bf16(s0[u * 4 + 2], s0[u * 4 + 3]);
            pw0[1][u] = cvt_pk_bf16(s1[u * 4 + 0], s1[u * 4 + 1]);
            pw1[1][u] = cvt_pk_bf16(s1[u * 4 + 2], s1[u * 4 + 3]);
        }

        // ---- O^T += V^T P^T over 4 kv-chunks of 16 ----
#pragma unroll
        for (int ksg = 0; ksg < 4; ++ksg) {
            const int b  = ksg >> 1;
            const int ks = ksg & 1;
            const unsigned a0 = pw0[b][2 * ks],     a1 = pw1[b][2 * ks];
            const unsigned b0 = pw0[b][2 * ks + 1], b1 = pw1[b][2 * ks + 1];
            const unsigned sa0 = __shfl_xor(a0, 32);
            const unsigned sb0 = __shfl_xor(b0, 32);
            const unsigned sa1 = __shfl_xor(a1, 32);
            const unsigned sb1 = __shfl_xor(b1, 32);
            union { unsigned wrd[4]; bf16x8 v; } pb;
            pb.wrd[0] = hi ? sb0 : a0;
            pb.wrd[1] = hi ? sb1 : a1;
            pb.wrd[2] = hi ? b0  : sa0;
            pb.wrd[3] = hi ? b1  : sa1;

            const unsigned short* Vk = Vh + kv0 + 16 * ksg + 8 * hi;
            {
                bf16x8 vf0 = *(const bf16x8*)(Vk + (size_t)(lq) * SEQ);
                o0_ = __builtin_amdgcn_mfma_f32_32x32x16_bf16(vf0, pb.v, o0_, 0, 0, 0);
                bf16x8 vf1 = *(const bf16x8*)(Vk + (size_t)(32 + lq) * SEQ);
                o1_ = __builtin_amdgcn_mfma_f32_32x32x16_bf16(vf1, pb.v, o1_, 0, 0, 0);
                bf16x8 vf2 = *(const bf16x8*)(Vk + (size_t)(64 + lq) * SEQ);
                o2_ = __builtin_amdgcn_mfma_f32_32x32x16_bf16(vf2, pb.v, o2_, 0, 0, 0);
                bf16x8 vf3 = *(const bf16x8*)(Vk + (size_t)(96 + lq) * SEQ);
                o3_ = __builtin_amdgcn_mfma_f32_32x32x16_bf16(vf3, pb.v, o3_, 0, 0, 0);
            }
        }
    }

    // ---- epilogue: normalize, pack pairs, store ----
    const float inv = 1.0f / lsum;
    unsigned short* orow = Ob + (size_t)qrow * DM + h * 128;
#pragma unroll
    for (int r = 0; r < 16; r += 2) {
        const int doff = 8 * (r >> 2) + 4 * hi + (r & 3);
        *(unsigned*)(orow + 0  + doff) = cvt_pk_bf16(o0_[r] * inv, o0_[r + 1] * inv);
        *(unsigned*)(orow + 32 + doff) = cvt_pk_bf16(o1_[r] * inv, o1_[r + 1] * inv);
        *(unsigned*)(orow + 64 + doff) = cvt_pk_bf16(o2_[r] * inv, o2_[r + 1] * inv);
        *(unsigned*)(orow + 96 + doff) = cvt_pk_bf16(o3_[r] * inv, o3_[r + 1] * inv);
    }
}

// ---------- launch ----------
extern "C" void kernel_launch(void* const* d_in, const int* in_sizes, int n_in,
                              void* d_out, int out_size, void* d_ws, size_t ws_size,
                              hipStream_t stream)
{
    const float* x  = (const float*)d_in[0];
    const float* Wq = (const float*)d_in[3];
    const float* Wk = (const float*)d_in[4];
    const float* Wv = (const float*)d_in[5];
    const float* Wo = (const float*)d_in[6];
    const float* qg = (const float*)d_in[7];
    const float* qb = (const float*)d_in[8];
    const float* kg = (const float*)d_in[9];
    const float* kb = (const float*)d_in[10];
    float* out = (float*)d_out;

    char* ws = (char*)d_ws;
    unsigned short* xb   = (unsigned short*)(ws);
    unsigned short* wqkv = (unsigned short*)(ws + 16777216);
    unsigned short* wo   = (unsigned short*)(ws + 67108864);
    float*          y    = (float*)        (ws + 100663296);
    unsigned short* qbuf = (unsigned short*)(ws + 150994944);
    unsigned short* kbuf = (unsigned short*)(ws + 167772160);
    unsigned short* vtb  = (unsigned short*)(ws + 171966464);
    unsigned short* ob   = (unsigned short*)(ws + 176160768);

    // 1) fp32 -> bf16 conversions
    {
        int n4 = (SEQ * DM) / 4;
        cvt_bf16<<<2048, 256, 0, stream>>>((const float4*)x, (ushort4*)xb, n4);
        n4 = (NQH * DK * DM) / 4;
        cvt_bf16<<<2048, 256, 0, stream>>>((const float4*)Wq, (ushort4*)wqkv, n4);
        n4 = (NKVH * DK * DM) / 4;
        cvt_bf16<<<2048, 256, 0, stream>>>((const float4*)Wk, (ushort4*)(wqkv + 16777216), n4);
        cvt_bf16<<<2048, 256, 0, stream>>>((const float4*)Wv, (ushort4*)(wqkv + 20971520), n4);
        n4 = (DM * DM) / 4;
        cvt_bf16<<<2048, 256, 0, stream>>>((const float4*)Wo, (ushort4*)wo, n4);
    }

    // 2) fused QKV projection: Y[2048][6144] = xb @ wqkv^T
    gemm_bt<<<dim3(NQKV / 128, SEQ / 128), 256, 0, stream>>>(xb, wqkv, y, SEQ, NQKV, DM);

    // 3) per-head LN on q,k -> bf16 head-major buffers (q pre-scaled)
    ln_qk<<<(SEQ * 40) / 4, 256, 0, stream>>>(y, qg, qb, kg, kb, qbuf, kbuf);

    // 4) V transpose -> Vt[8][128][2048]
    v_transpose<<<dim3(NKVH, SEQ / 64), 256, 0, stream>>>(y, vtb);

    // 5) causal GQA flash attention -> ob[2048][4096]
    attn<<<dim3(NQH, SEQ / 128), 256, 0, stream>>>(qbuf, kbuf, vtb, ob);

    // 6) output projection: out = ob @ wo^T (fp32 out)
    gemm_bt<<<dim3(DM / 128, SEQ / 128), 256, 0, stream>>>(ob, wo, out, SEQ, DM, DM);
}

// Round 4
// 527.871 us; speedup vs baseline: 1.2605x; 1.2154x over previous
//
#include <hip/hip_runtime.h>
#include <stdint.h>

typedef short bf16x8 __attribute__((ext_vector_type(8)));
typedef float f32x4 __attribute__((ext_vector_type(4)));
typedef float f32x16 __attribute__((ext_vector_type(16)));

#define SEQ     2048
#define DM      4096
#define NQH     32
#define NKVH    8
#define DK      128
#define NQKV    6144   // 4096 q + 1024 k + 1024 v

// ---------- helpers ----------
__device__ __forceinline__ unsigned short f2bfb(float f) {
    union { float f; unsigned u; } x; x.f = f;
    unsigned r = x.u + 0x7FFFu + ((x.u >> 16) & 1u);   // RNE
    return (unsigned short)(r >> 16);
}

__device__ __forceinline__ unsigned cvt_pk_bf16(float a, float b) {
    unsigned r;
    asm("v_cvt_pk_bf16_f32 %0, %1, %2" : "=v"(r) : "v"(a), "v"(b));
    return r;
}

#if __has_builtin(__builtin_amdgcn_exp2f)
__device__ __forceinline__ float exp2_fast(float x) { return __builtin_amdgcn_exp2f(x); }
#else
__device__ __forceinline__ float exp2_fast(float x) { return exp2f(x); }
#endif

__device__ __forceinline__ void stage16(const void* g, void* l) {
    __builtin_amdgcn_global_load_lds(
        (const __attribute__((address_space(1))) void*)g,
        (__attribute__((address_space(3))) void*)l,
        16, 0, 0);
}

// ---------- fp32 -> bf16 conversion (vectorized, grid-stride) ----------
__global__ __launch_bounds__(256)
void cvt_bf16(const float4* __restrict__ src, ushort4* __restrict__ dst, int n4) {
    int i = blockIdx.x * 256 + threadIdx.x;
    const int stride = gridDim.x * 256;
    for (; i < n4; i += stride) {
        float4 f = src[i];
        ushort4 u;
        u.x = f2bfb(f.x); u.y = f2bfb(f.y); u.z = f2bfb(f.z); u.w = f2bfb(f.w);
        dst[i] = u;
    }
}

// ---------- GEMM: C[M][N] = A[M][K](bf16) * B[N][K](bf16)^T, fp32 out ----------
__global__ __launch_bounds__(256, 2)
void gemm_bt(const unsigned short* __restrict__ A, const unsigned short* __restrict__ B,
             float* __restrict__ C, int M, int N, int K)
{
    __shared__ __align__(16) unsigned short As[128 * 32];
    __shared__ __align__(16) unsigned short Bs[128 * 32];

    const int tid = threadIdx.x;
    const int w  = tid >> 6;
    const int l  = tid & 63;
    const int lr = l & 15;
    const int lg = l >> 4;
    const int m0 = blockIdx.y << 7;
    const int n0 = blockIdx.x << 7;
    const int wm = (w >> 1) << 6;
    const int wn = (w & 1) << 6;

    f32x4 acc[4][4];
#pragma unroll
    for (int i = 0; i < 4; ++i)
#pragma unroll
        for (int j = 0; j < 4; ++j) acc[i][j] = f32x4{0.f, 0.f, 0.f, 0.f};

    const int c0   = tid;
    const int row0 = c0 >> 2, kc0 = (c0 & 3) << 3;
    const int c1   = tid + 256;
    const int row1 = c1 >> 2, kc1 = (c1 & 3) << 3;
    const unsigned short* Ag = A + (size_t)m0 * K;
    const unsigned short* Bg = B + (size_t)n0 * K;
    char* AsB = (char*)As;
    char* BsB = (char*)Bs;
    const int wb = w << 10;

    const int nk = K >> 5;
    for (int kt = 0; kt < nk; ++kt) {
        const int ko = kt << 5;
        stage16(Ag + (size_t)row0 * K + ko + kc0, AsB + wb);
        stage16(Ag + (size_t)row1 * K + ko + kc1, AsB + 4096 + wb);
        stage16(Bg + (size_t)row0 * K + ko + kc0, BsB + wb);
        stage16(Bg + (size_t)row1 * K + ko + kc1, BsB + 4096 + wb);
        __syncthreads();

        bf16x8 af[4], bfr[4];
#pragma unroll
        for (int mi = 0; mi < 4; ++mi)
            af[mi] = *(const bf16x8*)(As + ((wm + (mi << 4) + lr) << 5) + (lg << 3));
#pragma unroll
        for (int ni = 0; ni < 4; ++ni)
            bfr[ni] = *(const bf16x8*)(Bs + ((wn + (ni << 4) + lr) << 5) + (lg << 3));
#pragma unroll
        for (int mi = 0; mi < 4; ++mi)
#pragma unroll
            for (int ni = 0; ni < 4; ++ni)
                acc[mi][ni] = __builtin_amdgcn_mfma_f32_16x16x32_bf16(af[mi], bfr[ni], acc[mi][ni], 0, 0, 0);
        __syncthreads();
    }

#pragma unroll
    for (int mi = 0; mi < 4; ++mi)
#pragma unroll
        for (int ni = 0; ni < 4; ++ni) {
            const int row = m0 + wm + (mi << 4) + (lg << 2);
            const int col = n0 + wn + (ni << 4) + lr;
            float* cp = C + (size_t)row * N + col;
#pragma unroll
            for (int r = 0; r < 4; ++r) cp[(size_t)r * N] = acc[mi][ni][r];
        }
}

// ---------- per-head LayerNorm on q/k segments of Y, writes bf16 ----------
__global__ __launch_bounds__(256)
void ln_qk(const float* __restrict__ Y,
           const float* __restrict__ qg, const float* __restrict__ qb,
           const float* __restrict__ kg, const float* __restrict__ kb,
           unsigned short* __restrict__ Q, unsigned short* __restrict__ Kc)
{
    const int seg = blockIdx.x * 4 + (threadIdx.x >> 6);
    const int l = threadIdx.x & 63;
    const int s = seg / 40;
    const int hh = seg - s * 40;

    const float* y = Y + (size_t)s * NQKV + hh * 128;
    float2 v = *(const float2*)(y + l * 2);
    float sum = v.x + v.y;
    float sq  = v.x * v.x + v.y * v.y;
#pragma unroll
    for (int d = 1; d < 64; d <<= 1) {
        sum += __shfl_xor(sum, d);
        sq  += __shfl_xor(sq, d);
    }
    const float mu  = sum * (1.f / 128.f);
    const float var = sq * (1.f / 128.f) - mu * mu;
    const float rs  = rsqrtf(var + 1e-6f);

    const float* g = (hh < 32) ? qg : kg;
    const float* b = (hh < 32) ? qb : kb;
    // fold 1/sqrt(128)*log2(e) into the q-head LN output
    const float c = (hh < 32) ? (0.08838834764831845f * 1.4426950408889634f) : 1.0f;
    const float g0 = g[l * 2], g1 = g[l * 2 + 1];
    const float b0 = b[l * 2], b1 = b[l * 2 + 1];
    const unsigned short o0 = f2bfb(((v.x - mu) * rs * g0 + b0) * c);
    const unsigned short o1 = f2bfb(((v.y - mu) * rs * g1 + b1) * c);
    const unsigned pack = (unsigned)o0 | ((unsigned)o1 << 16);

    if (hh < 32) {
        unsigned* dst = (unsigned*)(Q + ((size_t)hh * SEQ + s) * 128 + l * 2);
        *dst = pack;
    } else {
        unsigned* dst = (unsigned*)(Kc + ((size_t)(hh - 32) * SEQ + s) * 128 + l * 2);
        *dst = pack;
    }
}

// ---------- V transpose: Y v-columns -> Vt[8][128][SEQ] bf16 ----------
__global__ __launch_bounds__(256)
void v_transpose(const float* __restrict__ Y, unsigned short* __restrict__ Vt)
{
    __shared__ unsigned short t[64][132];
    const int h  = blockIdx.x;
    const int s0 = blockIdx.y << 6;
    const int tid = threadIdx.x;
    const float* y = Y + (size_t)s0 * NQKV + 5120 + h * 128;

#pragma unroll
    for (int p = 0; p < 16; ++p) {
        const int idx = p * 512 + tid * 2;
        const int s = idx >> 7, d = idx & 127;
        float2 v = *(const float2*)(y + (size_t)s * NQKV + d);
        t[s][d]     = f2bfb(v.x);
        t[s][d + 1] = f2bfb(v.y);
    }
    __syncthreads();
    unsigned short* out = Vt + (size_t)h * 128 * SEQ + s0;
#pragma unroll
    for (int p = 0; p < 16; ++p) {
        const int idx = p * 512 + tid * 2;
        const int d = idx >> 6, sp = idx & 63;
        unsigned pack = (unsigned)t[sp][d] | ((unsigned)t[sp + 1][d] << 16);
        *(unsigned*)(out + (size_t)d * SEQ + sp) = pack;
    }
}

// ---------- causal GQA flash attention, swapped-operand + LDS-staged K/V ----------
// Q: [32][SEQ][128] (pre-scaled by 1/sqrt(d)*log2e), K: [8][SEQ][128],
// Vt: [8][128][SEQ], Ob: [SEQ][4096] bf16.
// Block: 4 waves x 32 q-rows = 128 q. KV tiles of 64, double-buffered in LDS,
// staged coalesced via global_load_lds with XOR swizzle (chunk ^= row&7) applied
// on the GLOBAL source (linear LDS dest), same XOR on ds_read addresses.
__global__ __launch_bounds__(256, 2)
void attn(const unsigned short* __restrict__ Qb, const unsigned short* __restrict__ Kb,
          const unsigned short* __restrict__ Vt, unsigned short* __restrict__ Ob)
{
    __shared__ __align__(16) unsigned short Kl[2][64 * 128];   // [kv][d], 16KB each
    __shared__ __align__(16) unsigned short Vl[2][128 * 64];   // [d][kv], 16KB each

    const int h   = blockIdx.x;
    const int qt  = 15 - blockIdx.y;        // heavy q-tiles first
    const int kvh = h >> 2;
    const int tid = threadIdx.x;
    const int w   = tid >> 6;
    const int l   = tid & 63;
    const int lq  = l & 31;                 // this lane's q (within wave)
    const int hi  = l >> 5;
    const int q0  = qt << 7;
    const int wq  = q0 + (w << 5);          // wave's q base
    const int qrow = wq + lq;

    const unsigned short* Qh = Qb + ((size_t)h * SEQ + wq) * 128;
    const unsigned short* Kh = Kb + (size_t)kvh * SEQ * 128;
    const unsigned short* Vh = Vt + (size_t)kvh * 128 * SEQ;

    // staging source offsets (element units), constant across tiles.
    // chunk c = p*256 + tid (16B each). K: row=c>>4 ch=c&15. V: row=c>>3 ch=c&7.
    int koff[4], voff[4];
#pragma unroll
    for (int p = 0; p < 4; ++p) {
        const int c  = p * 256 + tid;
        const int kr = c >> 4, kc = c & 15;
        koff[p] = kr * 128 + ((kc ^ (kr & 7)) << 3);
        const int vr = c >> 3, vc = c & 7;
        voff[p] = vr * SEQ + ((vc ^ (vr & 7)) << 3);
    }
    const int dstb = w << 10;               // wave-uniform LDS slice within a round

    // Q fragments (B-operand: col=lane&31=q, k-chunk=hi*8), all 8 d-steps
    bf16x8 qf[8];
#pragma unroll
    for (int ks = 0; ks < 8; ++ks)
        qf[ks] = *(const bf16x8*)(Qh + lq * 128 + ks * 16 + hi * 8);

    f32x16 o0_ = {0}, o1_ = {0}, o2_ = {0}, o3_ = {0};
    float m = -1.0e30f, lsum = 0.f;

    const int nt = (q0 + 128) >> 6;         // kv tiles this block needs
    const int sw = (lq & 7) << 4;           // read-side byte XOR (row&7 == lq&7 for all rows used)

    // prologue: stage tile 0 into buf 0
#pragma unroll
    for (int p = 0; p < 4; ++p)
        stage16(Kh + koff[p], (char*)Kl[0] + p * 4096 + dstb);
#pragma unroll
    for (int p = 0; p < 4; ++p)
        stage16(Vh + voff[p], (char*)Vl[0] + p * 4096 + dstb);
    __syncthreads();

    int buf = 0;
    for (int t = 0; t < nt; ++t) {
        const int kv0 = t << 6;

        // issue next-tile staging first (overlaps with compute below)
        if (t + 1 < nt) {
            const int kvn = kv0 + 64;
#pragma unroll
            for (int p = 0; p < 4; ++p)
                stage16(Kh + (size_t)kvn * 128 + koff[p], (char*)(Kl[buf ^ 1]) + p * 4096 + dstb);
#pragma unroll
            for (int p = 0; p < 4; ++p)
                stage16(Vh + kvn + voff[p], (char*)(Vl[buf ^ 1]) + p * 4096 + dstb);
        }

        if (kv0 <= wq + 31) {               // wave-uniform: skip fully-masked tiles
            // ---- QK^T from LDS ----
            const char* Kb0 = (const char*)(Kl[buf]) + lq * 256;
            const char* Kb1 = (const char*)(Kl[buf]) + (lq + 32) * 256;
            bf16x8 kf0[8], kf1[8];
#pragma unroll
            for (int ks = 0; ks < 8; ++ks) {
                const int cb = (ks * 32 + hi * 16) ^ sw;
                kf0[ks] = *(const bf16x8*)(Kb0 + cb);
                kf1[ks] = *(const bf16x8*)(Kb1 + cb);
            }
            f32x16 s0 = {0}, s1 = {0};
            __builtin_amdgcn_s_setprio(1);
#pragma unroll
            for (int ks = 0; ks < 8; ++ks) {
                s0 = __builtin_amdgcn_mfma_f32_32x32x16_bf16(kf0[ks], qf[ks], s0, 0, 0, 0);
                s1 = __builtin_amdgcn_mfma_f32_32x32x16_bf16(kf1[ks], qf[ks], s1, 0, 0, 0);
            }
            __builtin_amdgcn_s_setprio(0);

            // ---- causal mask (diagonal-crossing tiles only) ----
            if (kv0 + 63 > wq) {
#pragma unroll
                for (int r = 0; r < 16; ++r) {
                    const int kvl = (r & 3) + 8 * (r >> 2) + 4 * hi;
                    if (kv0 + kvl > qrow)      s0[r] = -1.0e30f;
                    if (kv0 + 32 + kvl > qrow) s1[r] = -1.0e30f;
                }
            }

            // ---- tree max over 32 values + cross-half combine ----
            float m8[8];
#pragma unroll
            for (int i = 0; i < 8; ++i)
                m8[i] = fmaxf(fmaxf(s0[i], s0[i + 8]), fmaxf(s1[i], s1[i + 8]));
#pragma unroll
            for (int i = 0; i < 4; ++i) m8[i] = fmaxf(m8[i], m8[i + 4]);
            float pm = fmaxf(fmaxf(m8[0], m8[1]), fmaxf(m8[2], m8[3]));
            pm = fmaxf(pm, __shfl_xor(pm, 32));

            // ---- defer-max (T13) ----
            if (!__all(pm - m <= 8.0f)) {
                const float mn = fmaxf(m, pm);
                const float al = exp2_fast(m - mn);
                lsum *= al;
#pragma unroll
                for (int r = 0; r < 16; ++r) { o0_[r] *= al; o1_[r] *= al; o2_[r] *= al; o3_[r] *= al; }
                m = mn;
            }

            // ---- p = exp2(s - m), tree row sum ----
#pragma unroll
            for (int r = 0; r < 16; ++r) s0[r] = exp2_fast(s0[r] - m);
#pragma unroll
            for (int r = 0; r < 16; ++r) s1[r] = exp2_fast(s1[r] - m);
            float a8[8];
#pragma unroll
            for (int i = 0; i < 8; ++i)
                a8[i] = (s0[i] + s0[i + 8]) + (s1[i] + s1[i + 8]);
#pragma unroll
            for (int i = 0; i < 4; ++i) a8[i] += a8[i + 4];
            float rs = (a8[0] + a8[1]) + (a8[2] + a8[3]);
            rs += __shfl_xor(rs, 32);
            lsum += rs;

            // ---- pack P to bf16 pair-words ----
            unsigned pw0[2][4], pw1[2][4];
#pragma unroll
            for (int u = 0; u < 4; ++u) {
                pw0[0][u] = cvt_pk_bf16(s0[u * 4 + 0], s0[u * 4 + 1]);
                pw1[0][u] = cvt_pk_bf16(s0[u * 4 + 2], s0[u * 4 + 3]);
                pw0[1][u] = cvt_pk_bf16(s1[u * 4 + 0], s1[u * 4 + 1]);
                pw1[1][u] = cvt_pk_bf16(s1[u * 4 + 2], s1[u * 4 + 3]);
            }

            // ---- O^T += V^T P^T, V frags from LDS ----
            const char* Vb = (const char*)(Vl[buf]);
#pragma unroll
            for (int ksg = 0; ksg < 4; ++ksg) {
                const int b  = ksg >> 1;
                const int ks = ksg & 1;
                const unsigned a0 = pw0[b][2 * ks],     a1 = pw1[b][2 * ks];
                const unsigned b0 = pw0[b][2 * ks + 1], b1 = pw1[b][2 * ks + 1];
                const unsigned sa0 = __shfl_xor(a0, 32);
                const unsigned sb0 = __shfl_xor(b0, 32);
                const unsigned sa1 = __shfl_xor(a1, 32);
                const unsigned sb1 = __shfl_xor(b1, 32);
                union { unsigned wrd[4]; bf16x8 v; } pb;
                pb.wrd[0] = hi ? sb0 : a0;
                pb.wrd[1] = hi ? sb1 : a1;
                pb.wrd[2] = hi ? b0  : sa0;
                pb.wrd[3] = hi ? b1  : sa1;

                const int cb = (ksg * 32 + hi * 16) ^ sw;
                bf16x8 vf0 = *(const bf16x8*)(Vb + (lq)       * 128 + cb);
                bf16x8 vf1 = *(const bf16x8*)(Vb + (lq + 32)  * 128 + cb);
                bf16x8 vf2 = *(const bf16x8*)(Vb + (lq + 64)  * 128 + cb);
                bf16x8 vf3 = *(const bf16x8*)(Vb + (lq + 96)  * 128 + cb);
                __builtin_amdgcn_s_setprio(1);
                o0_ = __builtin_amdgcn_mfma_f32_32x32x16_bf16(vf0, pb.v, o0_, 0, 0, 0);
                o1_ = __builtin_amdgcn_mfma_f32_32x32x16_bf16(vf1, pb.v, o1_, 0, 0, 0);
                o2_ = __builtin_amdgcn_mfma_f32_32x32x16_bf16(vf2, pb.v, o2_, 0, 0, 0);
                o3_ = __builtin_amdgcn_mfma_f32_32x32x16_bf16(vf3, pb.v, o3_, 0, 0, 0);
                __builtin_amdgcn_s_setprio(0);
            }
        }

        __syncthreads();    // drains vmcnt (staged tile ready) + protects LDS reuse
        buf ^= 1;
    }

    // ---- epilogue: normalize, pack pairs, store ----
    const float inv = 1.0f / lsum;
    unsigned short* orow = Ob + (size_t)qrow * DM + h * 128;
#pragma unroll
    for (int r = 0; r < 16; r += 2) {
        const int doff = 8 * (r >> 2) + 4 * hi + (r & 3);
        *(unsigned*)(orow + 0  + doff) = cvt_pk_bf16(o0_[r] * inv, o0_[r + 1] * inv);
        *(unsigned*)(orow + 32 + doff) = cvt_pk_bf16(o1_[r] * inv, o1_[r + 1] * inv);
        *(unsigned*)(orow + 64 + doff) = cvt_pk_bf16(o2_[r] * inv, o2_[r + 1] * inv);
        *(unsigned*)(orow + 96 + doff) = cvt_pk_bf16(o3_[r] * inv, o3_[r + 1] * inv);
    }
}

// ---------- launch ----------
extern "C" void kernel_launch(void* const* d_in, const int* in_sizes, int n_in,
                              void* d_out, int out_size, void* d_ws, size_t ws_size,
                              hipStream_t stream)
{
    const float* x  = (const float*)d_in[0];
    const float* Wq = (const float*)d_in[3];
    const float* Wk = (const float*)d_in[4];
    const float* Wv = (const float*)d_in[5];
    const float* Wo = (const float*)d_in[6];
    const float* qg = (const float*)d_in[7];
    const float* qb = (const float*)d_in[8];
    const float* kg = (const float*)d_in[9];
    const float* kb = (const float*)d_in[10];
    float* out = (float*)d_out;

    char* ws = (char*)d_ws;
    unsigned short* xb   = (unsigned short*)(ws);
    unsigned short* wqkv = (unsigned short*)(ws + 16777216);
    unsigned short* wo   = (unsigned short*)(ws + 67108864);
    float*          y    = (float*)        (ws + 100663296);
    unsigned short* qbuf = (unsigned short*)(ws + 150994944);
    unsigned short* kbuf = (unsigned short*)(ws + 167772160);
    unsigned short* vtb  = (unsigned short*)(ws + 171966464);
    unsigned short* ob   = (unsigned short*)(ws + 176160768);

    // 1) fp32 -> bf16 conversions
    {
        int n4 = (SEQ * DM) / 4;
        cvt_bf16<<<2048, 256, 0, stream>>>((const float4*)x, (ushort4*)xb, n4);
        n4 = (NQH * DK * DM) / 4;
        cvt_bf16<<<2048, 256, 0, stream>>>((const float4*)Wq, (ushort4*)wqkv, n4);
        n4 = (NKVH * DK * DM) / 4;
        cvt_bf16<<<2048, 256, 0, stream>>>((const float4*)Wk, (ushort4*)(wqkv + 16777216), n4);
        cvt_bf16<<<2048, 256, 0, stream>>>((const float4*)Wv, (ushort4*)(wqkv + 20971520), n4);
        n4 = (DM * DM) / 4;
        cvt_bf16<<<2048, 256, 0, stream>>>((const float4*)Wo, (ushort4*)wo, n4);
    }

    // 2) fused QKV projection: Y[2048][6144] = xb @ wqkv^T
    gemm_bt<<<dim3(NQKV / 128, SEQ / 128), 256, 0, stream>>>(xb, wqkv, y, SEQ, NQKV, DM);

    // 3) per-head LN on q,k -> bf16 head-major buffers (q pre-scaled)
    ln_qk<<<(SEQ * 40) / 4, 256, 0, stream>>>(y, qg, qb, kg, kb, qbuf, kbuf);

    // 4) V transpose -> Vt[8][128][2048]
    v_transpose<<<dim3(NKVH, SEQ / 64), 256, 0, stream>>>(y, vtb);

    // 5) causal GQA flash attention -> ob[2048][4096]
    attn<<<dim3(NQH, SEQ / 128), 256, 0, stream>>>(qbuf, kbuf, vtb, ob);

    // 6) output projection: out = ob @ wo^T (fp32 out)
    gemm_bt<<<dim3(DM / 128, SEQ / 128), 256, 0, stream>>>(ob, wo, out, SEQ, DM, DM);
}